// Round 1
// baseline (468.215 us; speedup 1.0000x reference)
//
#include <hip/hip_runtime.h>

// Problem constants (fixed by reference)
#define CI    16
#define CO    16
#define TAPS  9      // 3x3
#define HID   256
#define KPAD  288    // 256 + 32; k==256 row carries b2, k>256 zero
#define NKK   9      // KPAD/32 MFMA K-steps
#define NCH   144    // CI*TAPS columns per output channel
#define IMGH  128
#define IMGW  128
#define HSTR  296    // shH row stride (288 + 8 bf16 pad -> <=2-way LDS conflicts)

typedef float f32x4  __attribute__((ext_vector_type(4)));
typedef short bf16x8 __attribute__((ext_vector_type(8)));

__device__ __host__ __forceinline__ short f2bf(float f) {
  union { float f; unsigned u; } c; c.f = f;
  unsigned b = c.u + 0x7FFFu + ((c.u >> 16) & 1u);   // RNE
  return (short)(b >> 16);
}

// ---------------------------------------------------------------------------
// Prep: W2 [256][2304] fp32 (+ b2[2304]) -> W2b [o][kk][n:144][k:32] bf16,
// K padded to 288 (row 256 = b2, rows 257..287 = 0).
// LDS-transposed so both global reads and writes are coalesced.
// grid = 36 col-blocks * 9 kk = 324 blocks x 256 threads.
// ---------------------------------------------------------------------------
__global__ void prep_w2(const float* __restrict__ W2, const float* __restrict__ b2,
                        short* __restrict__ W2b) {
  __shared__ float tile[32][65];
  const int kk = blockIdx.x % NKK;
  const int colbase = (blockIdx.x / NKK) * 64;
  const int tid = threadIdx.x;

  for (int e = tid; e < 2048; e += 256) {
    int klr = e >> 6;          // 0..31
    int cc  = e & 63;
    int col = colbase + cc;
    float v;
    if (kk < 8) v = W2[(kk * 32 + klr) * (CO * NCH) + col];
    else        v = (klr == 0) ? b2[col] : 0.f;
    tile[klr][cc] = v;
  }
  __syncthreads();
  for (int e = tid; e < 2048; e += 256) {
    int cc = e >> 5;           // 0..63
    int kl = e & 31;
    int col = colbase + cc;
    int o = col / NCH;
    int n = col - o * NCH;
    W2b[(((o * NKK + kk) * NCH + n) << 5) + kl] = f2bf(tile[kl][cc]);
  }
}

// ---------------------------------------------------------------------------
// Main fused kernel. One block = 64 consecutive pixels of one image row.
// 4 waves; wave w computes output channels {w, w+4, w+8, w+12} for all 64
// pixels via MFMA 16x16x32 bf16 (M=pixels, N=144 per channel, K=288).
// grid = 4 batches * 128 rows * 2 half-rows = 1024 blocks x 256 threads.
// ---------------------------------------------------------------------------
__global__ __launch_bounds__(256, 2)
void ngconv_main(const float* __restrict__ in, const float* __restrict__ foa,
                 const float* __restrict__ W1, const float* __restrict__ b1,
                 const short* __restrict__ W2b, float* __restrict__ out) {
  __shared__ short shH[64 * HSTR];           // H tile, bf16, 37.9 KB
  __shared__ float shSlab[CI * 3 * 130];     // reflect-padded input slab, 25 KB

  const int tid  = threadIdx.x;
  const int lane = tid & 63;
  const int wv   = tid >> 6;
  const int c15  = lane & 15;
  const int quad = lane >> 4;

  const int blk = blockIdx.x;
  const int b   = blk >> 8;
  const int rem = blk & 255;
  const int y   = rem >> 1;
  const int x0  = (rem & 1) << 6;

  const float fx  = foa[b * 2 + 0];
  const float fy  = foa[b * 2 + 1];
  const float dyv = (float)y - fy;

  const int ry0 = (y == 0) ? 1 : (y - 1);
  const int ry2 = (y == IMGH - 1) ? (IMGH - 2) : (y + 1);

  // ---- input slab: 16 ch x 3 rows x [1..128], cols 0/129 are x-reflections
  for (int e = tid; e < CI * 3 * IMGW; e += 256) {
    int xs = e & 127;
    int rowid = e >> 7;                 // 0..47
    int i = rowid / 3, r = rowid - (rowid / 3) * 3;
    int ryr = (r == 0) ? ry0 : ((r == 1) ? y : ry2);
    shSlab[(i * 3 + r) * 130 + 1 + xs] =
        in[((b * CI + i) * IMGH + ryr) * IMGW + xs];
  }
  if (tid < CI * 3) {
    int i = tid / 3, r = tid - (tid / 3) * 3;
    int ryr = (r == 0) ? ry0 : ((r == 1) ? y : ry2);
    const float* src = &in[((b * CI + i) * IMGH + ryr) * IMGW];
    shSlab[(i * 3 + r) * 130 + 0]   = src[1];     // reflect(x=-1) -> 1
    shSlab[(i * 3 + r) * 130 + 129] = src[126];   // reflect(x=128) -> 126
  }

  // ---- H tile: h[row][k] = relu(dx*W1[0,k] + dy*W1[1,k] + b1[k]); k==256 -> 1
  for (int g = tid; g < 64 * (KPAD / 8); g += 256) {   // 2304 groups of 8 k
    int row = g / 36;
    int k0  = (g - row * 36) * 8;
    float dxv = (float)(x0 + row) - fx;
    short hv[8];
    if (k0 < HID) {
      #pragma unroll
      for (int j = 0; j < 8; ++j) {
        int k = k0 + j;
        float h = fmaxf(fmaf(dxv, W1[k], fmaf(dyv, W1[HID + k], b1[k])), 0.f);
        hv[j] = f2bf(h);
      }
    } else {
      #pragma unroll
      for (int j = 0; j < 8; ++j) hv[j] = (k0 + j == HID) ? f2bf(1.f) : (short)0;
    }
    *(bf16x8*)&shH[row * HSTR + k0] = *(bf16x8*)hv;
  }
  __syncthreads();

  // ---- per-lane patch LDS offsets: n = nt*16 + c15 -> (ci, dy, dx)
  int poff[9];
  #pragma unroll
  for (int nt = 0; nt < 9; ++nt) {
    int n15 = nt * 16 + c15;          // 0..143
    int i = n15 / 9;
    int q = n15 - i * 9;              // tap: dyr = q/3, dx+1 = q%3
    int dyr = q / 3;
    poff[nt] = (i * 3 + dyr) * 130 + (q - dyr * 3) + x0 + quad * 4;
  }

  // ---- main loop: 4 output channels per wave
  for (int oj = 0; oj < 4; ++oj) {
    const int o = wv + oj * 4;
    const short* Bp = W2b + (size_t)o * (NKK * NCH * 32);

    f32x4 acc[4][9];
    #pragma unroll
    for (int ms = 0; ms < 4; ++ms)
      #pragma unroll
      for (int nt = 0; nt < 9; ++nt)
        acc[ms][nt] = (f32x4){0.f, 0.f, 0.f, 0.f};

    for (int kk = 0; kk < NKK; ++kk) {
      bf16x8 af[4];
      #pragma unroll
      for (int ms = 0; ms < 4; ++ms)   // A: rows = pixels, ds_read_b128
        af[ms] = *(const bf16x8*)&shH[(ms * 16 + c15) * HSTR + kk * 32 + quad * 8];
      bf16x8 bfr[9];
      #pragma unroll
      for (int nt = 0; nt < 9; ++nt)   // B: W2b, 1 KiB coalesced L2 load/frag
        bfr[nt] = *(const bf16x8*)&Bp[((kk * NCH + nt * 16 + c15) << 5) + quad * 8];
      #pragma unroll
      for (int nt = 0; nt < 9; ++nt)
        #pragma unroll
        for (int ms = 0; ms < 4; ++ms)
          acc[ms][nt] = __builtin_amdgcn_mfma_f32_16x16x32_bf16(
              af[ms], bfr[nt], acc[ms][nt], 0, 0, 0);
    }

    // ---- epilogue: contract with patches; C layout row=quad*4+r, col=c15
    float P[16];
    #pragma unroll
    for (int ms = 0; ms < 4; ++ms)
      #pragma unroll
      for (int r = 0; r < 4; ++r) {
        float s = 0.f;
        #pragma unroll
        for (int nt = 0; nt < 9; ++nt)
          s = fmaf(acc[ms][nt][r], shSlab[poff[nt] + ms * 16 + r], s);
        P[ms * 4 + r] = s;
      }

    // reduce-scatter across the 16-lane column group:
    // after the loop, P[0] at lane = sum over group of original P[c15]
    #pragma unroll
    for (int m = 8; m >= 1; m >>= 1) {
      const bool hi = (c15 & m) != 0;
      #pragma unroll
      for (int j = 0; j < m; ++j) {
        float keep = hi ? P[j + m] : P[j];
        float send = hi ? P[j] : P[j + m];
        float recv = __shfl_xor(send, m, 64);
        P[j] = keep + recv;
      }
    }

    const int x = x0 + (c15 >> 2) * 16 + quad * 4 + (c15 & 3);
    out[((b * CO + o) * IMGH + y) * IMGW + x] = P[0];
  }
}

// ---------------------------------------------------------------------------
extern "C" void kernel_launch(void* const* d_in, const int* in_sizes, int n_in,
                              void* d_out, int out_size, void* d_ws, size_t ws_size,
                              hipStream_t stream) {
  const float* in  = (const float*)d_in[0];   // [4,16,128,128]
  const float* foa = (const float*)d_in[1];   // [4,2]
  const float* W1  = (const float*)d_in[2];   // [2,256]
  const float* b1  = (const float*)d_in[3];   // [256]
  const float* W2  = (const float*)d_in[4];   // [256,2304]
  const float* b2  = (const float*)d_in[5];   // [2304]
  float* out = (float*)d_out;
  short* W2b = (short*)d_ws;                  // 16*9*144*32 bf16 = 1.33 MB

  prep_w2<<<324, 256, 0, stream>>>(W2, b2, W2b);
  ngconv_main<<<1024, 256, 0, stream>>>(in, foa, W1, b1, W2b, out);
}

// Round 2
// 432.224 us; speedup vs baseline: 1.0833x; 1.0833x over previous
//
#include <hip/hip_runtime.h>

// Problem constants (fixed by reference)
#define CI    16
#define CO    16
#define TAPS  9      // 3x3
#define HID   256
#define KPAD  288    // 256 + 32; k==256 row carries b2, k>256 zero
#define NKK   9      // KPAD/32 MFMA K-steps
#define NCH   144    // CI*TAPS columns per output channel
#define IMGH  128
#define IMGW  128
#define HSTR  296    // shH row stride (288 + 8 bf16 pad -> <=2-way LDS conflicts)

typedef float f32x4  __attribute__((ext_vector_type(4)));
typedef short bf16x8 __attribute__((ext_vector_type(8)));

__device__ __host__ __forceinline__ short f2bf(float f) {
  union { float f; unsigned u; } c; c.f = f;
  unsigned b = c.u + 0x7FFFu + ((c.u >> 16) & 1u);   // RNE
  return (short)(b >> 16);
}

// ---------------------------------------------------------------------------
// Prep: W2 [256][2304] fp32 (+ b2[2304]) -> W2b [o][kk][n:144][k:32] bf16,
// K padded to 288 (row 256 = b2, rows 257..287 = 0).
// ---------------------------------------------------------------------------
__global__ void prep_w2(const float* __restrict__ W2, const float* __restrict__ b2,
                        short* __restrict__ W2b) {
  __shared__ float tile[32][65];
  const int kk = blockIdx.x % NKK;
  const int colbase = (blockIdx.x / NKK) * 64;
  const int tid = threadIdx.x;

  for (int e = tid; e < 2048; e += 256) {
    int klr = e >> 6;          // 0..31
    int cc  = e & 63;
    int col = colbase + cc;
    float v;
    if (kk < 8) v = W2[(kk * 32 + klr) * (CO * NCH) + col];
    else        v = (klr == 0) ? b2[col] : 0.f;
    tile[klr][cc] = v;
  }
  __syncthreads();
  for (int e = tid; e < 2048; e += 256) {
    int cc = e >> 5;           // 0..63
    int kl = e & 31;
    int col = colbase + cc;
    int o = col / NCH;
    int n = col - o * NCH;
    W2b[(((o * NKK + kk) * NCH + n) << 5) + kl] = f2bf(tile[kl][cc]);
  }
}

// ---------------------------------------------------------------------------
// Main fused kernel. One block = 64 consecutive pixels of one image row.
// 4 waves; wave w computes output channels {w, w+4, w+8, w+12} for all 64
// pixels via MFMA 16x16x32 bf16 (M=pixels, N=144 per channel, K=288).
// B fragments streamed with distance-1 prefetch (2 frags in flight) to keep
// the unified VGPR+AGPR count under 256 (2 blocks/CU, no spill).
// grid = 4 batches * 128 rows * 2 half-rows = 1024 blocks x 256 threads.
// ---------------------------------------------------------------------------
__global__ __launch_bounds__(256, 2)
void ngconv_main(const float* __restrict__ in, const float* __restrict__ foa,
                 const float* __restrict__ W1, const float* __restrict__ b1,
                 const short* __restrict__ W2b, float* __restrict__ out) {
  __shared__ short shH[64 * HSTR];           // H tile, bf16, 37.9 KB
  __shared__ float shSlab[CI * 3 * 130];     // reflect-padded input slab, 25 KB

  const int tid  = threadIdx.x;
  const int lane = tid & 63;
  const int wv   = tid >> 6;
  const int c15  = lane & 15;
  const int quad = lane >> 4;

  const int blk = blockIdx.x;
  const int b   = blk >> 8;
  const int rem = blk & 255;
  const int y   = rem >> 1;
  const int x0  = (rem & 1) << 6;

  const float fx  = foa[b * 2 + 0];
  const float fy  = foa[b * 2 + 1];
  const float dyv = (float)y - fy;

  const int ry0 = (y == 0) ? 1 : (y - 1);
  const int ry2 = (y == IMGH - 1) ? (IMGH - 2) : (y + 1);

  // ---- input slab: 16 ch x 3 rows x [1..128], cols 0/129 are x-reflections
  for (int e = tid; e < CI * 3 * IMGW; e += 256) {
    int xs = e & 127;
    int rowid = e >> 7;                 // 0..47
    int i = rowid / 3, r = rowid - (rowid / 3) * 3;
    int ryr = (r == 0) ? ry0 : ((r == 1) ? y : ry2);
    shSlab[(i * 3 + r) * 130 + 1 + xs] =
        in[((b * CI + i) * IMGH + ryr) * IMGW + xs];
  }
  if (tid < CI * 3) {
    int i = tid / 3, r = tid - (tid / 3) * 3;
    int ryr = (r == 0) ? ry0 : ((r == 1) ? y : ry2);
    const float* src = &in[((b * CI + i) * IMGH + ryr) * IMGW];
    shSlab[(i * 3 + r) * 130 + 0]   = src[1];     // reflect(x=-1) -> 1
    shSlab[(i * 3 + r) * 130 + 129] = src[126];   // reflect(x=128) -> 126
  }

  // ---- H tile: h[row][k] = relu(dx*W1[0,k] + dy*W1[1,k] + b1[k]); k==256 -> 1
  for (int g = tid; g < 64 * (KPAD / 8); g += 256) {   // 2304 groups of 8 k
    int row = g / 36;
    int k0  = (g - row * 36) * 8;
    float dxv = (float)(x0 + row) - fx;
    short hv[8];
    if (k0 < HID) {
      #pragma unroll
      for (int j = 0; j < 8; ++j) {
        int k = k0 + j;
        float h = fmaxf(fmaf(dxv, W1[k], fmaf(dyv, W1[HID + k], b1[k])), 0.f);
        hv[j] = f2bf(h);
      }
    } else {
      #pragma unroll
      for (int j = 0; j < 8; ++j) hv[j] = (k0 + j == HID) ? f2bf(1.f) : (short)0;
    }
    *(bf16x8*)&shH[row * HSTR + k0] = *(bf16x8*)hv;
  }
  __syncthreads();

  // ---- main loop: 4 output channels per wave, B frags streamed (prefetch 1)
  for (int oj = 0; oj < 4; ++oj) {
    const int o = wv + oj * 4;
    // per-lane base; frag f (= kk*9+nt) lives at Bl + f*512 (shorts)
    const short* Bl = W2b + (size_t)o * (NKK * NCH * 32) + (c15 << 5) + quad * 8;

    f32x4 acc[4][9];
    #pragma unroll
    for (int ms = 0; ms < 4; ++ms)
      #pragma unroll
      for (int nt = 0; nt < 9; ++nt)
        acc[ms][nt] = (f32x4){0.f, 0.f, 0.f, 0.f};

    bf16x8 bcur = *(const bf16x8*)&Bl[0];

    for (int kk = 0; kk < NKK; ++kk) {
      bf16x8 af[4];
      #pragma unroll
      for (int ms = 0; ms < 4; ++ms)   // A: rows = pixels, ds_read_b128
        af[ms] = *(const bf16x8*)&shH[(ms * 16 + c15) * HSTR + kk * 32 + quad * 8];
      #pragma unroll
      for (int nt = 0; nt < 9; ++nt) {
        int f = kk * 9 + nt;
        int fn = (f < 80) ? (f + 1) : 80;        // clamp: stay in-bounds
        bf16x8 bnext = *(const bf16x8*)&Bl[fn << 9];
        #pragma unroll
        for (int ms = 0; ms < 4; ++ms)
          acc[ms][nt] = __builtin_amdgcn_mfma_f32_16x16x32_bf16(
              af[ms], bcur, acc[ms][nt], 0, 0, 0);
        bcur = bnext;
      }
    }

    // ---- epilogue: contract with patches; C layout row=quad*4+r, col=c15
    // per-lane patch LDS offsets computed here (keeps MFMA-phase regs low)
    int poff[9];
    #pragma unroll
    for (int nt = 0; nt < 9; ++nt) {
      int n15 = nt * 16 + c15;          // 0..143
      int i = n15 / 9;
      int q = n15 - i * 9;              // tap: dyr = q/3, dx+1 = q%3
      int dyr = q / 3;
      poff[nt] = (i * 3 + dyr) * 130 + (q - dyr * 3) + x0 + quad * 4;
    }

    float P[16];
    #pragma unroll
    for (int ms = 0; ms < 4; ++ms)
      #pragma unroll
      for (int r = 0; r < 4; ++r) {
        float s = 0.f;
        #pragma unroll
        for (int nt = 0; nt < 9; ++nt)
          s = fmaf(acc[ms][nt][r], shSlab[poff[nt] + ms * 16 + r], s);
        P[ms * 4 + r] = s;
      }

    // reduce-scatter across the 16-lane column group
    #pragma unroll
    for (int m = 8; m >= 1; m >>= 1) {
      const bool hi = (c15 & m) != 0;
      #pragma unroll
      for (int j = 0; j < m; ++j) {
        float keep = hi ? P[j + m] : P[j];
        float send = hi ? P[j] : P[j + m];
        float recv = __shfl_xor(send, m, 64);
        P[j] = keep + recv;
      }
    }

    const int x = x0 + (c15 >> 2) * 16 + quad * 4 + (c15 & 3);
    out[((b * CO + o) * IMGH + y) * IMGW + x] = P[0];
  }
}

// ---------------------------------------------------------------------------
extern "C" void kernel_launch(void* const* d_in, const int* in_sizes, int n_in,
                              void* d_out, int out_size, void* d_ws, size_t ws_size,
                              hipStream_t stream) {
  const float* in  = (const float*)d_in[0];   // [4,16,128,128]
  const float* foa = (const float*)d_in[1];   // [4,2]
  const float* W1  = (const float*)d_in[2];   // [2,256]
  const float* b1  = (const float*)d_in[3];   // [256]
  const float* W2  = (const float*)d_in[4];   // [256,2304]
  const float* b2  = (const float*)d_in[5];   // [2304]
  float* out = (float*)d_out;
  short* W2b = (short*)d_ws;                  // 16*9*144*32 bf16 = 1.33 MB

  prep_w2<<<324, 256, 0, stream>>>(W2, b2, W2b);
  ngconv_main<<<1024, 256, 0, stream>>>(in, foa, W1, b1, W2b, out);
}